// Round 5
// baseline (3716.848 us; speedup 1.0000x reference)
//
#include <hip/hip_runtime.h>
#include <stdint.h>

typedef __bf16 bf16;
typedef __bf16 bf16x8 __attribute__((ext_vector_type(8)));
typedef float floatx4 __attribute__((ext_vector_type(4)));

#define EPS 1e-5f

__device__ __forceinline__ float wave_red_sum(float v) {
#pragma unroll
  for (int off = 32; off; off >>= 1) v += __shfl_xor(v, off, 64);
  return v;
}
__device__ __forceinline__ float wave_red_max(float v) {
#pragma unroll
  for (int off = 32; off; off >>= 1) v = fmaxf(v, __shfl_xor(v, off, 64));
  return v;
}
__device__ __forceinline__ float sigmoidf(float x) { return 1.f / (1.f + expf(-x)); }

__device__ __forceinline__ void gload_lds16(const bf16* g, bf16* l) {
  __builtin_amdgcn_global_load_lds(
      (const __attribute__((address_space(1))) char*)(g),
      (__attribute__((address_space(3))) char*)(l), 16, 0, 0);
}

// ---------------- weight transpose + cast: in fp32 [R,C] -> out bf16 [C,R] -------------
__global__ __launch_bounds__(256) void transpose_cast_kernel(
    const float* __restrict__ in, bf16* __restrict__ out, int R, int C) {
  __shared__ float tile[32][33];
  const size_t boff = (size_t)blockIdx.z * R * C;
  in += boff; out += boff;
  int tx = threadIdx.x, ty = threadIdx.y;
  int c0 = blockIdx.x * 32, r0 = blockIdx.y * 32;
#pragma unroll
  for (int j = 0; j < 32; j += 8)
    tile[ty + j][tx] = in[(size_t)(r0 + ty + j) * C + c0 + tx];
  __syncthreads();
#pragma unroll
  for (int j = 0; j < 32; j += 8)
    out[(size_t)(c0 + ty + j) * R + r0 + tx] = (bf16)tile[tx][ty + j];
}

// ---------------- MFMA GEMM, LDS-staged with XOR-swizzled k-groups (conflict-free).
template <int BM, int BN, int WM, int WN, int MODE>
__global__ __launch_bounds__(256) void gemm_kernel(
    const bf16* __restrict__ A, const bf16* __restrict__ Bt,
    const float* __restrict__ bias, bf16* __restrict__ outb,
    float* __restrict__ gsum, int N, int K) {
  constexpr int MI = WM / 16, NI = WN / 16, NWC = BN / WN;
  __shared__ bf16 As[BM * 64];
  __shared__ bf16 Bs[BN * 64];
  const int tid = threadIdx.x, l = tid & 63, w = tid >> 6;
  const int wr = w / NWC, wc = w % NWC;
  const int m0 = blockIdx.x * BM, n0 = blockIdx.y * BN;
  const int lrow8 = l >> 3;
  const int lcol8 = (((l & 7) ^ lrow8) * 8);  // XOR-swizzled k-group for staging
  const int quad = l >> 4, lane16 = l & 15;
  const int r7 = lane16 & 7;

  floatx4 acc[MI][NI];
#pragma unroll
  for (int mi = 0; mi < MI; ++mi)
#pragma unroll
    for (int ni = 0; ni < NI; ++ni) acc[mi][ni] = (floatx4){0.f, 0.f, 0.f, 0.f};

  const bf16* gA = A + (size_t)m0 * K;
  const bf16* gB = Bt + (size_t)n0 * K;

  for (int k0 = 0; k0 < K; k0 += 64) {
#pragma unroll
    for (int i = 0; i < BM / 32; ++i) {
      int rb = w * (BM / 4) + i * 8;
      gload_lds16(gA + (size_t)(rb + lrow8) * K + k0 + lcol8, As + rb * 64);
    }
#pragma unroll
    for (int i = 0; i < BN / 32; ++i) {
      int rb = w * (BN / 4) + i * 8;
      gload_lds16(gB + (size_t)(rb + lrow8) * K + k0 + lcol8, Bs + rb * 64);
    }
    __syncthreads();
#pragma unroll
    for (int kk = 0; kk < 64; kk += 32) {
      const int g = (kk >> 3) + quad;  // k-group 0..7
      bf16x8 af[MI], bfv[NI];
#pragma unroll
      for (int mi = 0; mi < MI; ++mi) {
        int r = wr * WM + mi * 16 + lane16;
        af[mi] = *(const bf16x8*)(As + r * 64 + ((g ^ r7) * 8));
      }
#pragma unroll
      for (int ni = 0; ni < NI; ++ni) {
        int r = wc * WN + ni * 16 + lane16;
        bfv[ni] = *(const bf16x8*)(Bs + r * 64 + ((g ^ r7) * 8));
      }
#pragma unroll
      for (int mi = 0; mi < MI; ++mi)
#pragma unroll
        for (int ni = 0; ni < NI; ++ni)
          acc[mi][ni] = __builtin_amdgcn_mfma_f32_16x16x32_bf16(af[mi], bfv[ni], acc[mi][ni], 0, 0, 0);
    }
    __syncthreads();
  }

  float psum[NI];
#pragma unroll
  for (int ni = 0; ni < NI; ++ni) psum[ni] = 0.f;

#pragma unroll
  for (int ni = 0; ni < NI; ++ni) {
    const int gn = n0 + wc * WN + ni * 16 + lane16;
    const float bv = bias[gn];
#pragma unroll
    for (int mi = 0; mi < MI; ++mi) {
#pragma unroll
      for (int i = 0; i < 4; ++i) {
        const int gm = m0 + wr * WM + mi * 16 + quad * 4 + i;
        float v = acc[mi][ni][i] + bv;
        if constexpr (MODE == 0) {
          float ge = 0.5f * v * (1.f + erff(v * 0.7071067811865475f));
          outb[(size_t)gm * N + gn] = (bf16)ge;
        } else {
          outb[(size_t)gm * N + gn] = (bf16)v;
          psum[ni] += v;
        }
      }
    }
  }
  if constexpr (MODE == 1) {
    float* cs = (float*)As;
    __syncthreads();
    for (int t = tid; t < BN; t += 256) cs[t] = 0.f;
    __syncthreads();
#pragma unroll
    for (int ni = 0; ni < NI; ++ni)
      atomicAdd(&cs[wc * WN + ni * 16 + lane16], psum[ni]);
    __syncthreads();
    for (int t = tid; t < BN; t += 256) atomicAdd(&gsum[n0 + t], cs[t]);
  }
}

// ---------------- direct single-slice GEMV: out[z,col] = alpha*sum_k v[z,k]*M[z][k*N+col] (+addv)
__global__ __launch_bounds__(256) void dgemv_kernel(
    const float* __restrict__ vin, int vstride, const float* __restrict__ M,
    size_t mstride, int K, int N, float alpha, const float* __restrict__ addv,
    float* __restrict__ outp, int ostride) {
  const int l = threadIdx.x & 63, wv = threadIdx.x >> 6;
  const int col = blockIdx.x * 64 + l;
  const int Kc = K >> 2;
  const int k0 = wv * Kc, k1 = k0 + Kc;
  const float* v = vin + (size_t)blockIdx.z * vstride;
  const float* Mp = M + (size_t)blockIdx.z * mstride;
  float acc = 0.f;
  for (int k = k0; k < k1; ++k) acc += v[k] * Mp[(size_t)k * N + col];
  __shared__ float sh[4][64];
  sh[wv][l] = acc;
  __syncthreads();
  if (wv == 0) {
    float r = (sh[0][l] + sh[1][l] + sh[2][l] + sh[3][l]) * alpha;
    if (addv) r += addv[col];
    outp[(size_t)blockIdx.z * ostride + col] = r;
  }
}

// ---------------- fused q = banks@s4_q then (last block) kq = scale * KM @ q
__global__ __launch_bounds__(256) void qk_fused_kernel(
    const float* __restrict__ banks, const float* __restrict__ s4q, int K,
    const float* __restrict__ KM, float scale, float* __restrict__ qbuf,
    float* __restrict__ kq, uint32_t* __restrict__ ticket) {
  const int tid = threadIdx.x, l = tid & 63, wv = tid >> 6;
  const int col = blockIdx.x * 64 + l;
  const int Kc = K >> 2;
  float acc = 0.f;
  for (int k = wv * Kc; k < (wv + 1) * Kc; ++k) acc += banks[k] * s4q[(size_t)k * 512 + col];
  __shared__ float sh[4][64];
  sh[wv][l] = acc;
  __syncthreads();
  if (wv == 0) qbuf[col] = sh[0][l] + sh[1][l] + sh[2][l] + sh[3][l];
  __threadfence();
  __shared__ uint32_t lastv;
  if (tid == 0) lastv = atomicAdd(ticket, 1u);
  __syncthreads();
  if (lastv != gridDim.x - 1) return;
  __threadfence();
  __shared__ float qs[512];
  qs[tid] = qbuf[tid]; qs[tid + 256] = qbuf[tid + 256];
  __syncthreads();
  for (int i = tid; i < 512; i += 256) {
    const float* row = KM + (size_t)i * 512;
    float a = 0.f;
#pragma unroll 4
    for (int j = 0; j < 512; ++j) a += row[j] * qs[j];
    kq[i] = a * scale;
  }
  if (tid == 0) atomicExch(ticket, 0u);
}

// ---------------- attention logits + (last block) softmax stats + cacc zero
__global__ __launch_bounds__(256) void attn_ls_kernel(
    const float* __restrict__ res, const float* __restrict__ s,
    const float* __restrict__ b, const float* __restrict__ kq,
    float* __restrict__ logits, float* __restrict__ stats,
    float* __restrict__ cacc, uint32_t* __restrict__ ticket) {
  const int tid = threadIdx.x, wid = tid >> 6, l = tid & 63;
  const int cb = l * 8;
#pragma unroll
  for (int rr = 0; rr < 2; ++rr) {
    const int row = blockIdx.x * 8 + rr * 4 + wid;
    const float* x = res + (size_t)row * 512 + cb;
    float4 a0 = *(const float4*)x, a1 = *(const float4*)(x + 4);
    float v[8] = {a0.x, a0.y, a0.z, a0.w, a1.x, a1.y, a1.z, a1.w};
    float sum = 0.f, sq = 0.f;
#pragma unroll
    for (int j = 0; j < 8; ++j) { sum += v[j]; sq += v[j] * v[j]; }
    sum = wave_red_sum(sum); sq = wave_red_sum(sq);
    float m = sum * (1.f / 512.f);
    float rstd = rsqrtf(sq * (1.f / 512.f) - m * m + EPS);
    float dot = 0.f;
#pragma unroll
    for (int j = 0; j < 8; ++j)
      dot += ((v[j] - m) * rstd * s[cb + j] + b[cb + j]) * kq[cb + j];
    dot = wave_red_sum(dot);
    if (l == 0) logits[row] = dot;
  }
  __threadfence();
  __shared__ uint32_t lastv;
  if (tid == 0) lastv = atomicAdd(ticket, 1u);
  __syncthreads();
  if (lastv != gridDim.x - 1) return;
  __threadfence();
  // wave wid handles batch wid
  float vv[32];
  const float* lp = logits + wid * 2048;
  float mx = -1e30f;
#pragma unroll
  for (int i = 0; i < 32; ++i) { vv[i] = lp[l + 64 * i]; mx = fmaxf(mx, vv[i]); }
  mx = wave_red_max(mx);
  float sum = 0.f;
#pragma unroll
  for (int i = 0; i < 32; ++i) sum += expf(vv[i] - mx);
  sum = wave_red_sum(sum);
  if (l == 0) { stats[wid] = mx; stats[4 + wid] = 1.f / sum; }
  for (int t = tid; t < 2048; t += 256) cacc[t] = 0.f;
  if (tid == 0) atomicExch(ticket, 0u);
}

// ---------------- weighted row-sum of LN(res); logits==null -> uniform 1/2048
__global__ __launch_bounds__(256) void wsum_kernel(
    const float* __restrict__ res, const float* __restrict__ s,
    const float* __restrict__ b, const float* __restrict__ logits,
    const float* __restrict__ stats, float* __restrict__ cout, int per_batch) {
  __shared__ float csh[512];
  const int tid = threadIdx.x, l = tid & 63, wv = tid >> 6;
  for (int t = tid; t < 512; t += 256) csh[t] = 0.f;
  __syncthreads();
  const int cb = l * 8;
  float sl[8], bl[8];
#pragma unroll
  for (int j = 0; j < 8; ++j) { sl[j] = s[cb + j]; bl[j] = b[cb + j]; }
  float pf[8] = {};
  const int base_row = blockIdx.x * 32;
  for (int rr = wv; rr < 32; rr += 4) {
    int row = base_row + rr;
    const float* x = res + (size_t)row * 512 + cb;
    float4 a0 = *(const float4*)x, a1 = *(const float4*)(x + 4);
    float v[8] = {a0.x, a0.y, a0.z, a0.w, a1.x, a1.y, a1.z, a1.w};
    float sum = 0.f, sq = 0.f;
#pragma unroll
    for (int j = 0; j < 8; ++j) { sum += v[j]; sq += v[j] * v[j]; }
    sum = wave_red_sum(sum); sq = wave_red_sum(sq);
    float m = sum * (1.f / 512.f);
    float rstd = rsqrtf(sq * (1.f / 512.f) - m * m + EPS);
    float aw;
    if (logits) {
      int bb = row >> 11;
      aw = expf(logits[row] - stats[bb]) * stats[4 + bb];
    } else {
      aw = 1.f / 2048.f;
    }
#pragma unroll
    for (int j = 0; j < 8; ++j) pf[j] += aw * ((v[j] - m) * rstd * sl[j] + bl[j]);
  }
#pragma unroll
  for (int j = 0; j < 8; ++j) atomicAdd(&csh[cb + j], pf[j]);
  __syncthreads();
  float* outp = cout + (per_batch ? (blockIdx.x >> 6) * 512 : 0);
  for (int t = tid; t < 512; t += 256) atomicAdd(&outp[t], csh[t]);
}

// ---------------- fused small gemvs + (last block) register-bank finalize
__global__ __launch_bounds__(256) void small_fused_kernel(
    const float* __restrict__ regs, float* __restrict__ summary,
    const float* __restrict__ gwp, const float* __restrict__ gbp,
    const float* __restrict__ wpp, float* __restrict__ gate_pre,
    float* __restrict__ ubuf, const float* __restrict__ wgw,
    const float* __restrict__ wgb, float* __restrict__ regsB,
    float* __restrict__ gp_next, uint32_t* __restrict__ ticket) {
  const int tid = threadIdx.x, l = tid & 63, wv = tid >> 6;
  const int z = blockIdx.z;
  if (!(z >= 2 && blockIdx.x >= 4)) {
    const float* v;
    const float* M;
    float* outp;
    int K; float alpha;
    if (z == 0)      { v = regs;    M = gwp;             outp = gate_pre; K = 768; alpha = 1.f; }
    else if (z == 1) { v = summary; M = gwp + 768 * 512; outp = gate_pre; K = 512; alpha = 1.f / 8192.f; }
    else { int r = z - 2; v = summary; M = wpp + (size_t)r * 512 * 256; outp = ubuf + r * 256; K = 512; alpha = 1.f / 8192.f; }
    const int N = (z < 2) ? 512 : 256;
    const int col = blockIdx.x * 64 + l;
    const int Kc = K >> 3;
    const int k0 = blockIdx.y * Kc, k1 = k0 + Kc;
    float acc = 0.f;
    for (int k = k0 + wv; k < k1; k += 4) acc += v[k] * M[(size_t)k * N + col];
    __shared__ float sh[4][64];
    sh[wv][l] = acc;
    __syncthreads();
    if (wv == 0) {
      float r = (sh[0][l] + sh[1][l] + sh[2][l] + sh[3][l]) * alpha;
      if (z == 0 && blockIdx.y == 0) r += gbp[col];
      atomicAdd(&outp[col], r);
    }
  }
  __threadfence();
  __shared__ uint32_t lastv;
  if (tid == 0) lastv = atomicAdd(ticket, 1u);
  __syncthreads();
  if (lastv != 320 - 1) return;
  __threadfence();
  __shared__ float wg[3];
  if (wv < 3) {
    float sg = 0.f;
    for (int d = l; d < 512; d += 64) sg += summary[d] * wgw[wv * 512 + d];
    sg = wave_red_sum(sg) * (1.f / 8192.f);
    if (l == 0) wg[wv] = sigmoidf(sg + wgb[wv]);
  }
  __syncthreads();
  for (int j = tid; j < 768; j += 256) regsB[j] = regs[j] + wg[j >> 8] * ubuf[j];
  __syncthreads();
  summary[tid] = 0.f; summary[tid + 256] = 0.f;
  gp_next[tid] = 0.f; gp_next[tid + 256] = 0.f;
  ubuf[tid] = 0.f; ubuf[tid + 256] = 0.f; ubuf[tid + 512] = 0.f;
  if (tid == 0) atomicExch(ticket, 0u);
}

// ---------------- first LN: reads x, writes residual copy + xn; block 0 zeroes buffers
__global__ __launch_bounds__(256) void ln_cast_first_kernel(
    const float* __restrict__ x, const float* __restrict__ s,
    const float* __restrict__ b, float* __restrict__ residual,
    bf16* __restrict__ xn, float* __restrict__ summary, float* __restrict__ gp0,
    float* __restrict__ gp1, float* __restrict__ ubuf, float* __restrict__ cacc) {
  if (blockIdx.x == 0) {
    const int t = threadIdx.x;
    summary[t] = 0.f; summary[t + 256] = 0.f;
    gp0[t] = 0.f; gp0[t + 256] = 0.f;
    gp1[t] = 0.f; gp1[t + 256] = 0.f;
    ubuf[t] = 0.f; ubuf[t + 256] = 0.f; ubuf[t + 512] = 0.f;
#pragma unroll
    for (int j = 0; j < 8; ++j) cacc[t * 8 + j] = 0.f;
  }
  const int wid = threadIdx.x >> 6, l = threadIdx.x & 63;
  const int row = blockIdx.x * 4 + wid;
  const int cb = l * 8;
  const float* xp = x + (size_t)row * 512 + cb;
  float4 a0 = *(const float4*)xp, a1 = *(const float4*)(xp + 4);
  float v[8] = {a0.x, a0.y, a0.z, a0.w, a1.x, a1.y, a1.z, a1.w};
  float* rp = residual + (size_t)row * 512 + cb;
  *(float4*)rp = a0; *(float4*)(rp + 4) = a1;
  float sum = 0.f, sq = 0.f;
#pragma unroll
  for (int j = 0; j < 8; ++j) { sum += v[j]; sq += v[j] * v[j]; }
  sum = wave_red_sum(sum); sq = wave_red_sum(sq);
  float m = sum * (1.f / 512.f);
  float rstd = rsqrtf(sq * (1.f / 512.f) - m * m + EPS);
  bf16x8 o;
#pragma unroll
  for (int j = 0; j < 8; ++j) o[j] = (bf16)((v[j] - m) * rstd * s[cb + j] + b[cb + j]);
  *(bf16x8*)(xn + (size_t)row * 512 + cb) = o;
}

// ---------------- fused residual update + LN/cast for the NEXT phase
__global__ __launch_bounds__(256) void resid_ln_kernel(
    float* __restrict__ res, const bf16* __restrict__ delta,
    const float* __restrict__ gp, const float* __restrict__ passw, int p,
    const float* __restrict__ s, const float* __restrict__ b,
    bf16* __restrict__ xn) {
  const int wid = threadIdx.x >> 6, l = threadIdx.x & 63;
  const int row = blockIdx.x * 4 + wid;
  const int cb = l * 8;
  const float pw = passw[p];
  float* x = res + (size_t)row * 512 + cb;
  float4 a0 = *(const float4*)x, a1 = *(const float4*)(x + 4);
  bf16x8 dv = *(const bf16x8*)(delta + (size_t)row * 512 + cb);
  float4 g0 = *(const float4*)(gp + cb), g1 = *(const float4*)(gp + cb + 4);
  float gg[8] = {g0.x, g0.y, g0.z, g0.w, g1.x, g1.y, g1.z, g1.w};
  float v[8] = {a0.x, a0.y, a0.z, a0.w, a1.x, a1.y, a1.z, a1.w};
#pragma unroll
  for (int j = 0; j < 8; ++j) v[j] += pw * sigmoidf(gg[j]) * (float)dv[j];
  *(float4*)x = make_float4(v[0], v[1], v[2], v[3]);
  *(float4*)(x + 4) = make_float4(v[4], v[5], v[6], v[7]);
  float sum = 0.f, sq = 0.f;
#pragma unroll
  for (int j = 0; j < 8; ++j) { sum += v[j]; sq += v[j] * v[j]; }
  sum = wave_red_sum(sum); sq = wave_red_sum(sq);
  float m = sum * (1.f / 512.f);
  float rstd = rsqrtf(sq * (1.f / 512.f) - m * m + EPS);
  bf16x8 o;
#pragma unroll
  for (int j = 0; j < 8; ++j) o[j] = (bf16)((v[j] - m) * rstd * s[cb + j] + b[cb + j]);
  *(bf16x8*)(xn + (size_t)row * 512 + cb) = o;
}

// ---------------- pass_w + ticket-counter zeroing (runs first)
__global__ __launch_bounds__(64) void passw_kernel(
    const float* __restrict__ reg_init, const float* __restrict__ ms3_w,
    const float* __restrict__ ms3_b, float* __restrict__ pass_w,
    uint32_t* __restrict__ tickets) {
  const int l = threadIdx.x;
  if (l < 16) tickets[l] = 0u;
  float acc[5] = {};
  for (int i = l; i < 3840; i += 64) {
    float v = reg_init[i % 768];
#pragma unroll
    for (int p = 0; p < 5; ++p) acc[p] += v * ms3_w[i * 5 + p];
  }
#pragma unroll
  for (int p = 0; p < 5; ++p) acc[p] = wave_red_sum(acc[p]);
  if (l < 5) pass_w[l] = sigmoidf(acc[l] + ms3_b[l]);
}

// ---------------- final: out = LN(res + outv[b]; out_ln)
__global__ __launch_bounds__(256) void final_out_kernel(
    const float* __restrict__ res, const float* __restrict__ outv,
    const float* __restrict__ s, const float* __restrict__ b,
    float* __restrict__ out) {
  const int wid = threadIdx.x >> 6, l = threadIdx.x & 63;
  const int row = blockIdx.x * 4 + wid;
  const int bidx = row >> 11, cb = l * 8;
  const float* x = res + (size_t)row * 512 + cb;
  const float* ov = outv + bidx * 512 + cb;
  float4 a0 = *(const float4*)x, a1 = *(const float4*)(x + 4);
  float v[8] = {a0.x, a0.y, a0.z, a0.w, a1.x, a1.y, a1.z, a1.w};
#pragma unroll
  for (int j = 0; j < 8; ++j) v[j] += ov[j];
  float sum = 0.f, sq = 0.f;
#pragma unroll
  for (int j = 0; j < 8; ++j) { sum += v[j]; sq += v[j] * v[j]; }
  sum = wave_red_sum(sum); sq = wave_red_sum(sq);
  float m = sum * (1.f / 512.f);
  float rstd = rsqrtf(sq * (1.f / 512.f) - m * m + EPS);
  float o[8];
#pragma unroll
  for (int j = 0; j < 8; ++j) o[j] = (v[j] - m) * rstd * s[cb + j] + b[cb + j];
  float* op = out + (size_t)row * 512 + cb;
  *(float4*)op = make_float4(o[0], o[1], o[2], o[3]);
  *(float4*)(op + 4) = make_float4(o[4], o[5], o[6], o[7]);
}

extern "C" void kernel_launch(void* const* d_in, const int* in_sizes, int n_in,
                              void* d_out, int out_size, void* d_ws, size_t ws_size,
                              hipStream_t stream) {
  const float* x        = (const float*)d_in[0];
  const float* reg_init = (const float*)d_in[1];
  const float* ffn_ln_s = (const float*)d_in[2];
  const float* ffn_ln_b = (const float*)d_in[3];
  const float* ffn_w1   = (const float*)d_in[4];
  const float* ffn_b1   = (const float*)d_in[5];
  const float* ffn_w2   = (const float*)d_in[6];
  const float* ffn_b2   = (const float*)d_in[7];
  const float* gate_w   = (const float*)d_in[8];
  const float* gate_b   = (const float*)d_in[9];
  const float* wproj_w  = (const float*)d_in[10];
  const float* wgate_w  = (const float*)d_in[11];
  const float* wgate_b  = (const float*)d_in[12];
  const float* s4_q     = (const float*)d_in[13];
  const float* s4_k     = (const float*)d_in[14];
  const float* s4_v     = (const float*)d_in[15];
  const float* s4_sum   = (const float*)d_in[16];
  const float* s4_ln_s  = (const float*)d_in[17];
  const float* s4_ln_b  = (const float*)d_in[18];
  const float* ms3_w    = (const float*)d_in[19];
  const float* ms3_b    = (const float*)d_in[20];
  const float* m4_q     = (const float*)d_in[21];
  const float* m4_k     = (const float*)d_in[22];
  const float* m4_v     = (const float*)d_in[23];
  const float* m4_out   = (const float*)d_in[24];
  const float* m4_ln_s  = (const float*)d_in[25];
  const float* m4_ln_b  = (const float*)d_in[26];
  const float* out_ln_s = (const float*)d_in[27];
  const float* out_ln_b = (const float*)d_in[28];
  float* out = (float*)d_out;

  char* wsp = (char*)d_ws;
  auto take = [&](size_t n) { char* p = wsp; wsp += (n + 255) & ~(size_t)255; return p; };
  float* residual = (float*)take(8192ull * 512 * 4);
  bf16*  xn       = (bf16*) take(8192ull * 512 * 2);
  bf16*  hbuf     = (bf16*) take(8192ull * 1536 * 2);
  bf16*  delta    = (bf16*) take(8192ull * 512 * 2);
  bf16*  w1t      = (bf16*) take(3ull * 1536 * 512 * 2);
  bf16*  w2t      = (bf16*) take(3ull * 512 * 1536 * 2);
  float* logits   = (float*)take(8192 * 4);
  float* stats    = (float*)take(8 * 4);
  float* cacc     = (float*)take(2048 * 4);
  float* qbuf     = (float*)take(512 * 4);
  float* kqbuf    = (float*)take(512 * 4);
  float* summary  = (float*)take(512 * 4);
  float* gp0      = (float*)take(512 * 4);
  float* gp1      = (float*)take(512 * 4);
  float* ubuf     = (float*)take(768 * 4);
  float* regsA    = (float*)take(768 * 4);
  float* regsB    = (float*)take(768 * 4);
  float* banks    = (float*)take(5 * 768 * 4);
  float* passw    = (float*)take(64);
  float* summv    = (float*)take(4 * 512 * 4);
  float* outv     = (float*)take(4 * 512 * 4);
  uint32_t* tickets = (uint32_t*)take(64 * 4);
  float* gpbuf[2] = {gp0, gp1};

  transpose_cast_kernel<<<dim3(1536 / 32, 512 / 32, 3), dim3(32, 8), 0, stream>>>(ffn_w1, w1t, 512, 1536);
  transpose_cast_kernel<<<dim3(512 / 32, 1536 / 32, 3), dim3(32, 8), 0, stream>>>(ffn_w2, w2t, 1536, 512);
  passw_kernel<<<1, 64, 0, stream>>>(reg_init, ms3_w, ms3_b, passw, tickets);
  ln_cast_first_kernel<<<2048, 256, 0, stream>>>(x, ffn_ln_s, ffn_ln_b, residual, xn,
                                                 summary, gp0, gp1, ubuf, cacc);

  const float scale = 0.04419417382415922f;  // 512^-0.5

  for (int p = 0; p < 5; ++p) {
    // s4_read (p=0: q==0 exactly -> uniform weights; cacc pre-zeroed by ln_cast_first)
    if (p > 0) {
      qk_fused_kernel<<<8, 256, 0, stream>>>(banks, s4_q, p * 768, s4_k, scale, qbuf, kqbuf, &tickets[0]);
      attn_ls_kernel<<<256, 256, 0, stream>>>(residual, s4_ln_s, s4_ln_b, kqbuf, logits, stats, cacc, &tickets[1]);
      wsum_kernel<<<256, 256, 0, stream>>>(residual, s4_ln_s, s4_ln_b, logits, stats, cacc, 0);
    } else {
      wsum_kernel<<<256, 256, 0, stream>>>(residual, s4_ln_s, s4_ln_b, nullptr, nullptr, cacc, 0);
    }
    dgemv_kernel<<<dim3(8, 1, 1), 256, 0, stream>>>(cacc, 0, s4_v, 0, 512, 512, 0.25f, nullptr, summv, 0);
    dgemv_kernel<<<dim3(12, 1, 1), 256, 0, stream>>>(summv, 0, s4_sum, 0, 512, 768, 1.f, reg_init, regsA, 0);

    float* cur = regsA;
    float* nxt = regsB;
    for (int ph = 0; ph < 3; ++ph) {
      const int pp = p * 3 + ph;
      gemm_kernel<128, 128, 64, 64, 0><<<dim3(64, 12), 256, 0, stream>>>(
          xn, w1t + (size_t)ph * 1536 * 512, ffn_b1 + ph * 1536, hbuf, nullptr, 1536, 512);
      gemm_kernel<128, 64, 64, 32, 1><<<dim3(64, 8), 256, 0, stream>>>(
          hbuf, w2t + (size_t)ph * 512 * 1536, ffn_b2 + ph * 512, delta, summary, 512, 1536);
      float* nx = (ph == 2) ? (banks + p * 768) : nxt;
      small_fused_kernel<<<dim3(8, 8, 5), 256, 0, stream>>>(
          cur, summary, gate_w + (size_t)pp * 1280 * 512, gate_b + pp * 512,
          wproj_w + (size_t)pp * 3 * 512 * 256, gpbuf[pp & 1], ubuf,
          wgate_w + pp * 3 * 512, wgate_b + pp * 3, nx, gpbuf[(pp + 1) & 1], &tickets[2]);
      // fused residual update + LN for next phase ((ph+1)%3; at pp=14 xn unused)
      const int nph = (ph + 1) % 3;
      resid_ln_kernel<<<2048, 256, 0, stream>>>(residual, delta, gpbuf[pp & 1], passw, p,
                                                ffn_ln_s + nph * 512, ffn_ln_b + nph * 512, xn);
      float* t = cur; cur = nx; nxt = (ph == 0) ? regsA : regsB; (void)t;
    }
  }

  // MetaS4
  qk_fused_kernel<<<8, 256, 0, stream>>>(banks, m4_q, 3840, m4_k, scale, qbuf, kqbuf, &tickets[0]);
  attn_ls_kernel<<<256, 256, 0, stream>>>(residual, m4_ln_s, m4_ln_b, kqbuf, logits, stats, cacc, &tickets[1]);
  wsum_kernel<<<256, 256, 0, stream>>>(residual, m4_ln_s, m4_ln_b, logits, stats, cacc, 1);
  dgemv_kernel<<<dim3(8, 1, 4), 256, 0, stream>>>(cacc, 512, m4_v, 0, 512, 512, 1.f, nullptr, summv, 512);
  dgemv_kernel<<<dim3(8, 1, 4), 256, 0, stream>>>(summv, 512, m4_out, 0, 512, 512, 1.f, nullptr, outv, 512);
  final_out_kernel<<<2048, 256, 0, stream>>>(residual, outv, out_ln_s, out_ln_b, out);
}

// Round 7
// 2032.610 us; speedup vs baseline: 1.8286x; 1.8286x over previous
//
#include <hip/hip_runtime.h>
#include <stdint.h>

typedef __bf16 bf16;
typedef __bf16 bf16x8 __attribute__((ext_vector_type(8)));
typedef float floatx4 __attribute__((ext_vector_type(4)));

#define EPS 1e-5f

__device__ __forceinline__ float wave_red_sum(float v) {
#pragma unroll
  for (int off = 32; off; off >>= 1) v += __shfl_xor(v, off, 64);
  return v;
}
__device__ __forceinline__ float sigmoidf(float x) { return 1.f / (1.f + expf(-x)); }

__device__ __forceinline__ void gload_lds16(const bf16* g, bf16* l) {
  __builtin_amdgcn_global_load_lds(
      (const __attribute__((address_space(1))) char*)(g),
      (__attribute__((address_space(3))) char*)(l), 16, 0, 0);
}

// ---------------- weight transpose + cast: in fp32 [R,C] -> out bf16 [C,R] -------------
__global__ __launch_bounds__(256) void transpose_cast_kernel(
    const float* __restrict__ in, bf16* __restrict__ out, int R, int C) {
  __shared__ float tile[32][33];
  const size_t boff = (size_t)blockIdx.z * R * C;
  in += boff; out += boff;
  int tx = threadIdx.x, ty = threadIdx.y;
  int c0 = blockIdx.x * 32, r0 = blockIdx.y * 32;
#pragma unroll
  for (int j = 0; j < 32; j += 8)
    tile[ty + j][tx] = in[(size_t)(r0 + ty + j) * C + c0 + tx];
  __syncthreads();
#pragma unroll
  for (int j = 0; j < 32; j += 8)
    out[(size_t)(c0 + ty + j) * R + r0 + tx] = (bf16)tile[tx][ty + j];
}

// ---------------- MFMA GEMM, LDS-staged with XOR-swizzled k-groups (conflict-free).
template <int BM, int BN, int WM, int WN, int MODE>
__global__ __launch_bounds__(256) void gemm_kernel(
    const bf16* __restrict__ A, const bf16* __restrict__ Bt,
    const float* __restrict__ bias, bf16* __restrict__ outb,
    float* __restrict__ gsum, int N, int K) {
  constexpr int MI = WM / 16, NI = WN / 16, NWC = BN / WN;
  __shared__ bf16 As[BM * 64];
  __shared__ bf16 Bs[BN * 64];
  const int tid = threadIdx.x, l = tid & 63, w = tid >> 6;
  const int wr = w / NWC, wc = w % NWC;
  const int m0 = blockIdx.x * BM, n0 = blockIdx.y * BN;
  const int lrow8 = l >> 3;
  const int lcol8 = (((l & 7) ^ lrow8) * 8);  // XOR-swizzled k-group for staging
  const int quad = l >> 4, lane16 = l & 15;
  const int r7 = lane16 & 7;

  floatx4 acc[MI][NI];
#pragma unroll
  for (int mi = 0; mi < MI; ++mi)
#pragma unroll
    for (int ni = 0; ni < NI; ++ni) acc[mi][ni] = (floatx4){0.f, 0.f, 0.f, 0.f};

  const bf16* gA = A + (size_t)m0 * K;
  const bf16* gB = Bt + (size_t)n0 * K;

  for (int k0 = 0; k0 < K; k0 += 64) {
#pragma unroll
    for (int i = 0; i < BM / 32; ++i) {
      int rb = w * (BM / 4) + i * 8;
      gload_lds16(gA + (size_t)(rb + lrow8) * K + k0 + lcol8, As + rb * 64);
    }
#pragma unroll
    for (int i = 0; i < BN / 32; ++i) {
      int rb = w * (BN / 4) + i * 8;
      gload_lds16(gB + (size_t)(rb + lrow8) * K + k0 + lcol8, Bs + rb * 64);
    }
    __syncthreads();
#pragma unroll
    for (int kk = 0; kk < 64; kk += 32) {
      const int g = (kk >> 3) + quad;  // k-group 0..7
      bf16x8 af[MI], bfv[NI];
#pragma unroll
      for (int mi = 0; mi < MI; ++mi) {
        int r = wr * WM + mi * 16 + lane16;
        af[mi] = *(const bf16x8*)(As + r * 64 + ((g ^ r7) * 8));
      }
#pragma unroll
      for (int ni = 0; ni < NI; ++ni) {
        int r = wc * WN + ni * 16 + lane16;
        bfv[ni] = *(const bf16x8*)(Bs + r * 64 + ((g ^ r7) * 8));
      }
#pragma unroll
      for (int mi = 0; mi < MI; ++mi)
#pragma unroll
        for (int ni = 0; ni < NI; ++ni)
          acc[mi][ni] = __builtin_amdgcn_mfma_f32_16x16x32_bf16(af[mi], bfv[ni], acc[mi][ni], 0, 0, 0);
    }
    __syncthreads();
  }

  float psum[NI];
#pragma unroll
  for (int ni = 0; ni < NI; ++ni) psum[ni] = 0.f;

#pragma unroll
  for (int ni = 0; ni < NI; ++ni) {
    const int gn = n0 + wc * WN + ni * 16 + lane16;
    const float bv = bias[gn];
#pragma unroll
    for (int mi = 0; mi < MI; ++mi) {
#pragma unroll
      for (int i = 0; i < 4; ++i) {
        const int gm = m0 + wr * WM + mi * 16 + quad * 4 + i;
        float v = acc[mi][ni][i] + bv;
        if constexpr (MODE == 0) {
          float ge = 0.5f * v * (1.f + erff(v * 0.7071067811865475f));
          outb[(size_t)gm * N + gn] = (bf16)ge;
        } else {
          outb[(size_t)gm * N + gn] = (bf16)v;
          psum[ni] += v;
        }
      }
    }
  }
  if constexpr (MODE == 1) {
    float* cs = (float*)As;
    __syncthreads();
    for (int t = tid; t < BN; t += 256) cs[t] = 0.f;
    __syncthreads();
#pragma unroll
    for (int ni = 0; ni < NI; ++ni)
      atomicAdd(&cs[wc * WN + ni * 16 + lane16], psum[ni]);
    __syncthreads();
    for (int t = tid; t < BN; t += 256) atomicAdd(&gsum[n0 + t], cs[t]);
  }
}

// ---------------- split-K atomic GEMV with optional 1/Z weighting.
// zmode 0: w_k = alpha, row k. zmode 1: w_k = alpha/Zp[k>>9], row (k&511).
// zmode 2: w_k = alpha/Zp[blockIdx.z], row k.
__global__ __launch_bounds__(256) void gemv_kernel(
    const float* __restrict__ vin, int vstride, const float* __restrict__ M,
    size_t mstride, int K, int N, float alpha, const float* __restrict__ Zp,
    int zmode, float* __restrict__ outp, int ostride) {
  const int l = threadIdx.x & 63, wv = threadIdx.x >> 6;
  const int col = blockIdx.x * 64 + l;
  const int KS = gridDim.y;
  const int Kc = (K + KS - 1) / KS;
  const int k0 = blockIdx.y * Kc;
  const int k1 = min(K, k0 + Kc);
  const float* v = vin + (size_t)blockIdx.z * vstride;
  const float* Mp = M + (size_t)blockIdx.z * mstride;
  float sc[4] = {alpha, alpha, alpha, alpha};
  if (zmode == 1) {
#pragma unroll
    for (int b = 0; b < 4; ++b) sc[b] = alpha / Zp[b];
  } else if (zmode == 2) {
    sc[0] = alpha / Zp[blockIdx.z];
  }
  float acc = 0.f;
  if (zmode == 1) {
    // batch-folded: same 512-row matrix per batch, weight varies per batch
    for (int k = k0 + wv; k < k1; k += 4)
      acc += v[k] * sc[k >> 9] * Mp[(size_t)(k & 511) * N + col];
  } else {
    for (int k = k0 + wv; k < k1; k += 4)
      acc += v[k] * Mp[(size_t)k * N + col];
    acc *= sc[0];
  }
  __shared__ float sh[4][64];
  sh[wv][l] = acc;
  __syncthreads();
  if (wv == 0) {
    float r = sh[0][l] + sh[1][l] + sh[2][l] + sh[3][l];
    atomicAdd(&outp[(size_t)blockIdx.z * ostride + col], r);
  }
}

// ---------------- init helper: a[na]=0, b[nb]=0, c[nc]=csrc?csrc:0
__global__ __launch_bounds__(256) void init3_kernel(
    float* __restrict__ a, int na, float* __restrict__ b, int nb,
    float* __restrict__ c, const float* __restrict__ csrc, int nc) {
  const int t = blockIdx.x * 256 + threadIdx.x;
  if (t < na) a[t] = 0.f;
  if (t < nb) b[t] = 0.f;
  if (t < nc) c[t] = csrc ? csrc[t] : 0.f;
}

// ---------------- kq = scale * (KM @ q), one wave per row
__global__ __launch_bounds__(256) void kq_kernel(
    const float* __restrict__ KM, const float* __restrict__ q, float scale,
    float* __restrict__ kq) {
  const int d = blockIdx.x * 4 + (threadIdx.x >> 6), l = threadIdx.x & 63;
  float a = 0.f;
  for (int j = l; j < 512; j += 64) a += KM[(size_t)d * 512 + j] * q[j];
  a = wave_red_sum(a);
  if (l == 0) kq[d] = a * scale;
}

// ---------------- fused attention: per row LN -> logit -> aw=exp(logit) ->
// accumulate aw*xn into cacc4[batch] and aw into Z[batch]. kq==null -> aw=1.
__global__ __launch_bounds__(256) void attn_wsum_kernel(
    const float* __restrict__ res, const float* __restrict__ s,
    const float* __restrict__ b, const float* __restrict__ kq,
    float* __restrict__ cacc4, float* __restrict__ Z) {
  __shared__ float csh[512];
  __shared__ float zsh[4];
  const int tid = threadIdx.x, l = tid & 63, wv = tid >> 6;
  for (int t = tid; t < 512; t += 256) csh[t] = 0.f;
  if (tid < 4) zsh[tid] = 0.f;
  __syncthreads();
  const int cb = l * 8;
  float sl[8], bl[8], kl[8];
#pragma unroll
  for (int j = 0; j < 8; ++j) { sl[j] = s[cb + j]; bl[j] = b[cb + j]; }
  if (kq) {
#pragma unroll
    for (int j = 0; j < 8; ++j) kl[j] = kq[cb + j];
  }
  float pf[8] = {};
  float zacc = 0.f;
  const int base_row = blockIdx.x * 32;
  for (int rr = wv; rr < 32; rr += 4) {
    int row = base_row + rr;
    const float* x = res + (size_t)row * 512 + cb;
    float4 a0 = *(const float4*)x, a1 = *(const float4*)(x + 4);
    float v[8] = {a0.x, a0.y, a0.z, a0.w, a1.x, a1.y, a1.z, a1.w};
    float sum = 0.f, sq = 0.f;
#pragma unroll
    for (int j = 0; j < 8; ++j) { sum += v[j]; sq += v[j] * v[j]; }
    sum = wave_red_sum(sum); sq = wave_red_sum(sq);
    float m = sum * (1.f / 512.f);
    float rstd = rsqrtf(sq * (1.f / 512.f) - m * m + EPS);
    float xn[8];
#pragma unroll
    for (int j = 0; j < 8; ++j) xn[j] = (v[j] - m) * rstd * sl[j] + bl[j];
    float aw = 1.f;
    if (kq) {
      float dot = 0.f;
#pragma unroll
      for (int j = 0; j < 8; ++j) dot += xn[j] * kl[j];
      dot = wave_red_sum(dot);
      aw = expf(dot);  // |dot| << 1 here: raw exp is safe (no max-subtract)
    }
#pragma unroll
    for (int j = 0; j < 8; ++j) pf[j] += aw * xn[j];
    if (l == 0) zacc += aw;
  }
#pragma unroll
  for (int j = 0; j < 8; ++j) atomicAdd(&csh[cb + j], pf[j]);
  if (l == 0) atomicAdd(&zsh[0], zacc);
  __syncthreads();
  const int batch = blockIdx.x >> 6;
  float* outp = cacc4 + batch * 512;
  for (int t = tid; t < 512; t += 256) atomicAdd(&outp[t], csh[t]);
  if (tid == 0) atomicAdd(&Z[batch], zsh[0]);
}

// ---------------- fused small gemvs + (last block) register-bank finalize
__global__ __launch_bounds__(256) void small_fused_kernel(
    const float* __restrict__ regs, float* __restrict__ summary,
    const float* __restrict__ gwp, const float* __restrict__ gbp,
    const float* __restrict__ wpp, float* __restrict__ gate_pre,
    float* __restrict__ ubuf, const float* __restrict__ wgw,
    const float* __restrict__ wgb, float* __restrict__ regsB,
    float* __restrict__ gp_next, uint32_t* __restrict__ ticket) {
  const int tid = threadIdx.x, l = tid & 63, wv = tid >> 6;
  const int z = blockIdx.z;
  if (!(z >= 2 && blockIdx.x >= 4)) {
    const float* v;
    const float* M;
    float* outp;
    int K; float alpha;
    if (z == 0)      { v = regs;    M = gwp;             outp = gate_pre; K = 768; alpha = 1.f; }
    else if (z == 1) { v = summary; M = gwp + 768 * 512; outp = gate_pre; K = 512; alpha = 1.f / 8192.f; }
    else { int r = z - 2; v = summary; M = wpp + (size_t)r * 512 * 256; outp = ubuf + r * 256; K = 512; alpha = 1.f / 8192.f; }
    const int N = (z < 2) ? 512 : 256;
    const int col = blockIdx.x * 64 + l;
    const int Kc = K >> 3;
    const int k0 = blockIdx.y * Kc, k1 = k0 + Kc;
    float acc = 0.f;
    for (int k = k0 + wv; k < k1; k += 4) acc += v[k] * M[(size_t)k * N + col];
    __shared__ float sh[4][64];
    sh[wv][l] = acc;
    __syncthreads();
    if (wv == 0) {
      float r = (sh[0][l] + sh[1][l] + sh[2][l] + sh[3][l]) * alpha;
      if (z == 0 && blockIdx.y == 0) r += gbp[col];
      atomicAdd(&outp[col], r);
    }
  }
  __threadfence();
  __shared__ uint32_t lastv;
  if (tid == 0) lastv = atomicAdd(ticket, 1u);
  __syncthreads();
  if (lastv != 320 - 1) return;
  __threadfence();
  __shared__ float wg[3];
  if (wv < 3) {
    float sg = 0.f;
    for (int d = l; d < 512; d += 64) sg += summary[d] * wgw[wv * 512 + d];
    sg = wave_red_sum(sg) * (1.f / 8192.f);
    if (l == 0) wg[wv] = sigmoidf(sg + wgb[wv]);
  }
  __syncthreads();
  for (int j = tid; j < 768; j += 256) regsB[j] = regs[j] + wg[j >> 8] * ubuf[j];
  __syncthreads();
  summary[tid] = 0.f; summary[tid + 256] = 0.f;
  gp_next[tid] = 0.f; gp_next[tid + 256] = 0.f;
  ubuf[tid] = 0.f; ubuf[tid + 256] = 0.f; ubuf[tid + 512] = 0.f;
  if (tid == 0) atomicExch(ticket, 0u);
}

// ---------------- first LN: reads x, writes residual copy + xn; block 0 zeroes buffers
__global__ __launch_bounds__(256) void ln_cast_first_kernel(
    const float* __restrict__ x, const float* __restrict__ s,
    const float* __restrict__ b, float* __restrict__ residual,
    bf16* __restrict__ xn, float* __restrict__ summary, float* __restrict__ gp0,
    float* __restrict__ gp1, float* __restrict__ ubuf) {
  if (blockIdx.x == 0) {
    const int t = threadIdx.x;
    summary[t] = 0.f; summary[t + 256] = 0.f;
    gp0[t] = 0.f; gp0[t + 256] = 0.f;
    gp1[t] = 0.f; gp1[t + 256] = 0.f;
    ubuf[t] = 0.f; ubuf[t + 256] = 0.f; ubuf[t + 512] = 0.f;
  }
  const int wid = threadIdx.x >> 6, l = threadIdx.x & 63;
  const int row = blockIdx.x * 4 + wid;
  const int cb = l * 8;
  const float* xp = x + (size_t)row * 512 + cb;
  float4 a0 = *(const float4*)xp, a1 = *(const float4*)(xp + 4);
  float v[8] = {a0.x, a0.y, a0.z, a0.w, a1.x, a1.y, a1.z, a1.w};
  float* rp = residual + (size_t)row * 512 + cb;
  *(float4*)rp = a0; *(float4*)(rp + 4) = a1;
  float sum = 0.f, sq = 0.f;
#pragma unroll
  for (int j = 0; j < 8; ++j) { sum += v[j]; sq += v[j] * v[j]; }
  sum = wave_red_sum(sum); sq = wave_red_sum(sq);
  float m = sum * (1.f / 512.f);
  float rstd = rsqrtf(sq * (1.f / 512.f) - m * m + EPS);
  bf16x8 o;
#pragma unroll
  for (int j = 0; j < 8; ++j) o[j] = (bf16)((v[j] - m) * rstd * s[cb + j] + b[cb + j]);
  *(bf16x8*)(xn + (size_t)row * 512 + cb) = o;
}

// ---------------- fused residual update + LN/cast for the NEXT phase (xn==null: skip LN)
__global__ __launch_bounds__(256) void resid_ln_kernel(
    float* __restrict__ res, const bf16* __restrict__ delta,
    const float* __restrict__ gp, const float* __restrict__ passw, int p,
    const float* __restrict__ s, const float* __restrict__ b,
    bf16* __restrict__ xn) {
  const int wid = threadIdx.x >> 6, l = threadIdx.x & 63;
  const int row = blockIdx.x * 4 + wid;
  const int cb = l * 8;
  const float pw = passw[p];
  float* x = res + (size_t)row * 512 + cb;
  float4 a0 = *(const float4*)x, a1 = *(const float4*)(x + 4);
  bf16x8 dv = *(const bf16x8*)(delta + (size_t)row * 512 + cb);
  float4 g0 = *(const float4*)(gp + cb), g1 = *(const float4*)(gp + cb + 4);
  float gg[8] = {g0.x, g0.y, g0.z, g0.w, g1.x, g1.y, g1.z, g1.w};
  float v[8] = {a0.x, a0.y, a0.z, a0.w, a1.x, a1.y, a1.z, a1.w};
#pragma unroll
  for (int j = 0; j < 8; ++j) v[j] += pw * sigmoidf(gg[j]) * (float)dv[j];
  *(float4*)x = make_float4(v[0], v[1], v[2], v[3]);
  *(float4*)(x + 4) = make_float4(v[4], v[5], v[6], v[7]);
  if (!xn) return;
  float sum = 0.f, sq = 0.f;
#pragma unroll
  for (int j = 0; j < 8; ++j) { sum += v[j]; sq += v[j] * v[j]; }
  sum = wave_red_sum(sum); sq = wave_red_sum(sq);
  float m = sum * (1.f / 512.f);
  float rstd = rsqrtf(sq * (1.f / 512.f) - m * m + EPS);
  bf16x8 o;
#pragma unroll
  for (int j = 0; j < 8; ++j) o[j] = (bf16)((v[j] - m) * rstd * s[cb + j] + b[cb + j]);
  *(bf16x8*)(xn + (size_t)row * 512 + cb) = o;
}

// ---------------- pass_w + ticket-counter zeroing (runs first)
__global__ __launch_bounds__(64) void passw_kernel(
    const float* __restrict__ reg_init, const float* __restrict__ ms3_w,
    const float* __restrict__ ms3_b, float* __restrict__ pass_w,
    uint32_t* __restrict__ tickets) {
  const int l = threadIdx.x;
  if (l < 16) tickets[l] = 0u;
  float acc[5] = {};
  for (int i = l; i < 3840; i += 64) {
    float v = reg_init[i % 768];
#pragma unroll
    for (int p = 0; p < 5; ++p) acc[p] += v * ms3_w[i * 5 + p];
  }
#pragma unroll
  for (int p = 0; p < 5; ++p) acc[p] = wave_red_sum(acc[p]);
  if (l < 5) pass_w[l] = sigmoidf(acc[l] + ms3_b[l]);
}

// ---------------- final: out = LN(res + outv[b]; out_ln)
__global__ __launch_bounds__(256) void final_out_kernel(
    const float* __restrict__ res, const float* __restrict__ outv,
    const float* __restrict__ s, const float* __restrict__ b,
    float* __restrict__ out) {
  const int wid = threadIdx.x >> 6, l = threadIdx.x & 63;
  const int row = blockIdx.x * 4 + wid;
  const int bidx = row >> 11, cb = l * 8;
  const float* x = res + (size_t)row * 512 + cb;
  const float* ov = outv + bidx * 512 + cb;
  float4 a0 = *(const float4*)x, a1 = *(const float4*)(x + 4);
  float v[8] = {a0.x, a0.y, a0.z, a0.w, a1.x, a1.y, a1.z, a1.w};
#pragma unroll
  for (int j = 0; j < 8; ++j) v[j] += ov[j];
  float sum = 0.f, sq = 0.f;
#pragma unroll
  for (int j = 0; j < 8; ++j) { sum += v[j]; sq += v[j] * v[j]; }
  sum = wave_red_sum(sum); sq = wave_red_sum(sq);
  float m = sum * (1.f / 512.f);
  float rstd = rsqrtf(sq * (1.f / 512.f) - m * m + EPS);
  float o[8];
#pragma unroll
  for (int j = 0; j < 8; ++j) o[j] = (v[j] - m) * rstd * s[cb + j] + b[cb + j];
  float* op = out + (size_t)row * 512 + cb;
  *(float4*)op = make_float4(o[0], o[1], o[2], o[3]);
  *(float4*)(op + 4) = make_float4(o[4], o[5], o[6], o[7]);
}

extern "C" void kernel_launch(void* const* d_in, const int* in_sizes, int n_in,
                              void* d_out, int out_size, void* d_ws, size_t ws_size,
                              hipStream_t stream) {
  const float* x        = (const float*)d_in[0];
  const float* reg_init = (const float*)d_in[1];
  const float* ffn_ln_s = (const float*)d_in[2];
  const float* ffn_ln_b = (const float*)d_in[3];
  const float* ffn_w1   = (const float*)d_in[4];
  const float* ffn_b1   = (const float*)d_in[5];
  const float* ffn_w2   = (const float*)d_in[6];
  const float* ffn_b2   = (const float*)d_in[7];
  const float* gate_w   = (const float*)d_in[8];
  const float* gate_b   = (const float*)d_in[9];
  const float* wproj_w  = (const float*)d_in[10];
  const float* wgate_w  = (const float*)d_in[11];
  const float* wgate_b  = (const float*)d_in[12];
  const float* s4_q     = (const float*)d_in[13];
  const float* s4_k     = (const float*)d_in[14];
  const float* s4_v     = (const float*)d_in[15];
  const float* s4_sum   = (const float*)d_in[16];
  const float* s4_ln_s  = (const float*)d_in[17];
  const float* s4_ln_b  = (const float*)d_in[18];
  const float* ms3_w    = (const float*)d_in[19];
  const float* ms3_b    = (const float*)d_in[20];
  const float* m4_q     = (const float*)d_in[21];
  const float* m4_k     = (const float*)d_in[22];
  const float* m4_v     = (const float*)d_in[23];
  const float* m4_out   = (const float*)d_in[24];
  const float* m4_ln_s  = (const float*)d_in[25];
  const float* m4_ln_b  = (const float*)d_in[26];
  const float* out_ln_s = (const float*)d_in[27];
  const float* out_ln_b = (const float*)d_in[28];
  float* out = (float*)d_out;

  char* wsp = (char*)d_ws;
  auto take = [&](size_t n) { char* p = wsp; wsp += (n + 255) & ~(size_t)255; return p; };
  float* residual = (float*)take(8192ull * 512 * 4);
  bf16*  xn       = (bf16*) take(8192ull * 512 * 2);
  bf16*  hbuf     = (bf16*) take(8192ull * 1536 * 2);
  bf16*  delta    = (bf16*) take(8192ull * 512 * 2);
  bf16*  w1t      = (bf16*) take(3ull * 1536 * 512 * 2);
  bf16*  w2t      = (bf16*) take(3ull * 512 * 1536 * 2);
  float* attnbuf  = (float*)take(2564 * 4);   // cacc4[2048] | Z[4] | qbuf[512]
  float* cacc4    = attnbuf;
  float* Zb       = attnbuf + 2048;
  float* qbuf     = attnbuf + 2052;
  float* kqbuf    = (float*)take(512 * 4);
  float* summary  = (float*)take(512 * 4);
  float* gp0      = (float*)take(512 * 4);
  float* gp1      = (float*)take(512 * 4);
  float* ubuf     = (float*)take(768 * 4);
  float* regsA    = (float*)take(768 * 4);
  float* regsB    = (float*)take(768 * 4);
  float* banks    = (float*)take(5 * 768 * 4);
  float* passw    = (float*)take(64);
  float* summv    = (float*)take(4 * 512 * 4);
  float* outv     = (float*)take(4 * 512 * 4);
  uint32_t* tickets = (uint32_t*)take(64 * 4);
  float* gpbuf[2] = {gp0, gp1};

  transpose_cast_kernel<<<dim3(1536 / 32, 512 / 32, 3), dim3(32, 8), 0, stream>>>(ffn_w1, w1t, 512, 1536);
  transpose_cast_kernel<<<dim3(512 / 32, 1536 / 32, 3), dim3(32, 8), 0, stream>>>(ffn_w2, w2t, 1536, 512);
  passw_kernel<<<1, 64, 0, stream>>>(reg_init, ms3_w, ms3_b, passw, tickets);
  ln_cast_first_kernel<<<2048, 256, 0, stream>>>(x, ffn_ln_s, ffn_ln_b, residual, xn,
                                                 summary, gp0, gp1, ubuf);

  const float scale = 0.04419417382415922f;  // 512^-0.5

  for (int p = 0; p < 5; ++p) {
    // attnbuf (cacc4+Z+qbuf) = 0, summv = 0, regsA = reg_init
    init3_kernel<<<11, 256, 0, stream>>>(attnbuf, 2564, summv, 512, regsA, reg_init, 768);
    if (p > 0) {
      gemv_kernel<<<dim3(8, 4 * (p + 1), 1), 256, 0, stream>>>(
          banks, 0, s4_q, 0, p * 768, 512, 1.f, nullptr, 0, qbuf, 0);
      kq_kernel<<<128, 256, 0, stream>>>(s4_k, qbuf, scale, kqbuf);
      attn_wsum_kernel<<<256, 256, 0, stream>>>(residual, s4_ln_s, s4_ln_b, kqbuf, cacc4, Zb);
    } else {
      // q == 0 exactly -> aw = 1 path
      attn_wsum_kernel<<<256, 256, 0, stream>>>(residual, s4_ln_s, s4_ln_b, nullptr, cacc4, Zb);
    }
    // summv = 0.25 * sum_b (cacc4[b]/Z[b]) @ s4_v   (batch-folded, row = k&511)
    gemv_kernel<<<dim3(8, 8, 1), 256, 0, stream>>>(cacc4, 0, s4_v, 0, 2048, 512, 0.25f, Zb, 1, summv, 0);
    // regsA += summv @ s4_sum
    gemv_kernel<<<dim3(12, 8, 1), 256, 0, stream>>>(summv, 0, s4_sum, 0, 512, 768, 1.f, nullptr, 0, regsA, 0);

    float* cur = regsA;
    float* nxt = regsB;
    for (int ph = 0; ph < 3; ++ph) {
      const int pp = p * 3 + ph;
      gemm_kernel<128, 128, 64, 64, 0><<<dim3(64, 12), 256, 0, stream>>>(
          xn, w1t + (size_t)ph * 1536 * 512, ffn_b1 + ph * 1536, hbuf, nullptr, 1536, 512);
      gemm_kernel<128, 64, 64, 32, 1><<<dim3(64, 8), 256, 0, stream>>>(
          hbuf, w2t + (size_t)ph * 512 * 1536, ffn_b2 + ph * 512, delta, summary, 512, 1536);
      float* nx = (ph == 2) ? (banks + p * 768) : nxt;
      small_fused_kernel<<<dim3(8, 8, 5), 256, 0, stream>>>(
          cur, summary, gate_w + (size_t)pp * 1280 * 512, gate_b + pp * 512,
          wproj_w + (size_t)pp * 3 * 512 * 256, gpbuf[pp & 1], ubuf,
          wgate_w + pp * 3 * 512, wgate_b + pp * 3, nx, gpbuf[(pp + 1) & 1], &tickets[2]);
      const int nph = (ph + 1) % 3;
      resid_ln_kernel<<<2048, 256, 0, stream>>>(residual, delta, gpbuf[pp & 1], passw, p,
                                                ffn_ln_s + nph * 512, ffn_ln_b + nph * 512,
                                                (pp == 14) ? nullptr : xn);
      float* t = cur; cur = nx; nxt = (ph == 0) ? regsA : regsB; (void)t;
    }
  }

  // MetaS4: attnbuf = 0, summv+outv = 0 (contiguous 4096)
  init3_kernel<<<16, 256, 0, stream>>>(attnbuf, 2564, summv, 4096, nullptr, nullptr, 0);
  gemv_kernel<<<dim3(8, 16, 1), 256, 0, stream>>>(banks, 0, m4_q, 0, 3840, 512, 1.f, nullptr, 0, qbuf, 0);
  kq_kernel<<<128, 256, 0, stream>>>(m4_k, qbuf, scale, kqbuf);
  attn_wsum_kernel<<<256, 256, 0, stream>>>(residual, m4_ln_s, m4_ln_b, kqbuf, cacc4, Zb);
  // summv[b] = (cacc4[b]/Z[b]) @ m4_v ; outv[b] = summv[b] @ m4_out
  gemv_kernel<<<dim3(8, 8, 4), 256, 0, stream>>>(cacc4, 512, m4_v, 0, 512, 512, 1.f, Zb, 2, summv, 512);
  gemv_kernel<<<dim3(8, 8, 4), 256, 0, stream>>>(summv, 512, m4_out, 0, 512, 512, 1.f, nullptr, 0, outv, 512);
  final_out_kernel<<<2048, 256, 0, stream>>>(residual, outv, out_ln_s, out_ln_b, out);
}